// Round 5
// baseline (253.011 us; speedup 1.0000x reference)
//
#include <hip/hip_runtime.h>
#include <cstdint>
#include <cmath>

#define S_LEN 2048
#define D_DIM 1024
#define NH    16
#define DKD   64
#define BATCH 4
#define M_TOT (BATCH * S_LEN)   // 8192

// 0.125 * log2(e): folded into Q so QK^T lands directly in exp2 domain
#define QSCALE 0.18033688011112042f

typedef __attribute__((ext_vector_type(8)))  short bf16x8;
typedef __attribute__((ext_vector_type(4)))  float f32x4;
typedef __attribute__((ext_vector_type(16))) float f32x16;

typedef __attribute__((address_space(1))) void as1_void;
typedef __attribute__((address_space(3))) void as3_void;

__device__ __forceinline__ short f2b(float f) {
    union { float f; uint32_t u; } v; v.f = f;
    uint32_t r = v.u + 0x7fffu + ((v.u >> 16) & 1u);   // RNE
    return (short)(r >> 16);
}

__device__ __forceinline__ void gld_lds16(const void* g, void* l) {
    __builtin_amdgcn_global_load_lds((as1_void*)g, (as3_void*)l, 16, 0, 0);
}

__device__ __forceinline__ float fast_exp2(float x) {
#if __has_builtin(__builtin_amdgcn_exp2f)
    return __builtin_amdgcn_exp2f(x);
#else
    return exp2f(x);
#endif
}

__device__ __forceinline__ uint32_t cvtpk(float lo, float hi) {
    uint32_t r;
    asm("v_cvt_pk_bf16_f32 %0, %1, %2" : "=v"(r) : "v"(lo), "v"(hi));
    return r;
}

// two genuinely-distinct values: validated by R2 (T12 packing)
__device__ __forceinline__ void pl32swap(uint32_t& a, uint32_t& b) {
    asm volatile("v_permlane32_swap_b32 %0, %1" : "+v"(a), "+v"(b));
}

// ---------------- cast x (fp32 -> bf16), 8 elems/thread ----------------
__global__ __launch_bounds__(256) void cast_x_k(const float* __restrict__ x,
                                                short* __restrict__ xb) {
    size_t i = (size_t)blockIdx.x * 256 + threadIdx.x;
    const float4* p = (const float4*)x + i * 2;
    float4 a = p[0], b = p[1];
    bf16x8 o;
    o[0]=f2b(a.x); o[1]=f2b(a.y); o[2]=f2b(a.z); o[3]=f2b(a.w);
    o[4]=f2b(b.x); o[5]=f2b(b.y); o[6]=f2b(b.z); o[7]=f2b(b.w);
    *((bf16x8*)xb + i) = o;
}

// ---------------- transpose + cast weights: Wt[n][k] = W[k][n] ----------------
__global__ __launch_bounds__(256) void cast_wt_k(const float* w0, const float* w1,
                                                 const float* w2, const float* w3,
                                                 short* o0, short* o1, short* o2, short* o3) {
    __shared__ float tile[32][33];
    const float* src = blockIdx.z == 0 ? w0 : blockIdx.z == 1 ? w1 : blockIdx.z == 2 ? w2 : w3;
    short*       dst = blockIdx.z == 0 ? o0 : blockIdx.z == 1 ? o1 : blockIdx.z == 2 ? o2 : o3;
    int tx = threadIdx.x, ty = threadIdx.y;
    int bx = blockIdx.x * 32, by = blockIdx.y * 32;
    #pragma unroll
    for (int i = 0; i < 4; ++i)
        tile[ty * 4 + i][tx] = src[(size_t)(by + ty * 4 + i) * D_DIM + bx + tx];
    __syncthreads();
    #pragma unroll
    for (int i = 0; i < 4; ++i)
        dst[(size_t)(bx + ty * 4 + i) * D_DIM + by + tx] = f2b(tile[tx][ty * 4 + i]);
}

// ---------------- RoPE table: ctab/stab [S][32] ----------------
__global__ __launch_bounds__(256) void rope_tab_k(float* __restrict__ ct, float* __restrict__ st) {
    int i = blockIdx.x * 256 + threadIdx.x;      // 2048*32 = 65536
    int s = i >> 5, tt = i & 31;
    float inv = (float)pow(10000.0, -(double)(2 * tt) / 64.0);
    float ang = (float)s * inv;
    float sn, cs;
    sincosf(ang, &sn, &cs);
    ct[i] = cs; st[i] = sn;
}

// ---------------- fused QKV GEMM: C[M][3072] = A[M][K] * BT[3072][K]^T -------------
// Natural block order: gridDim.x=24 (24%8==0) => XCD = bx%8 => each XCD owns
// bx in {k,k+8,k+16}: 3 B-panels (768 KB) stay L2-resident; A streams via L3.
// Double-buffered LDS, ONE barrier per K-step: stage(next) overlaps compute(cur).
__global__ __launch_bounds__(256) void gemm_qkv_k(const short* __restrict__ A,
                                                  const short* __restrict__ BT,
                                                  short* __restrict__ Qb,
                                                  short* __restrict__ Kb,
                                                  short* __restrict__ Vt,
                                                  const float* __restrict__ ctab,
                                                  const float* __restrict__ stab) {
    const int K = 1024;
    __shared__ short As[2][128 * 64];   // 2 x 16 KB
    __shared__ short Bs[2][128 * 64];   // 2 x 16 KB  (total 64 KB -> 2 blocks/CU)

    const int bx = blockIdx.x;          // 0..23
    const int by = blockIdx.y;          // 0..63

    const int t = threadIdx.x;
    const int lane = t & 63;
    const int li = lane & 15;
    const int g  = lane >> 4;
    const int w  = t >> 6;
    const int wr = w >> 1, wc = w & 1;
    const int mbase = by * 128;
    const int nbase = bx * 128;
    const int seg   = bx >> 3;          // 0=Q 1=K 2=V (block-uniform)

    f32x4 acc[4][4] = {};

    auto stageAB = [&](int bb, int kt) {
        const int k0 = kt * 64;
        #pragma unroll
        for (int it = 0; it < 4; ++it) {
            int idx = it * 256 + t;
            int r = idx >> 3, p = idx & 7;
            int c = p ^ (r & 7);
            gld_lds16(A + (size_t)(mbase + r) * K + k0 + c * 8, &As[bb][idx * 8]);
        }
        #pragma unroll
        for (int it = 0; it < 4; ++it) {
            int idx = it * 256 + t;
            int r = idx >> 3, p = idx & 7;
            int c = p ^ (r & 7);
            gld_lds16(BT + (size_t)(nbase + r) * K + k0 + c * 8, &Bs[bb][idx * 8]);
        }
    };

    stageAB(0, 0);
    int buf = 0;
    for (int kt = 0; kt < K / 64; ++kt) {
        __syncthreads();                                   // own stage drained; tile ready
        if (kt + 1 < K / 64) stageAB(buf ^ 1, kt + 1);     // prefetch overlaps compute

        #pragma unroll
        for (int kk = 0; kk < 2; ++kk) {
            bf16x8 af[4], bfr[4];
            #pragma unroll
            for (int mt = 0; mt < 4; ++mt) {
                int row = wr * 64 + mt * 16 + li;
                int c = (kk * 4 + g) ^ (row & 7);
                af[mt] = *(const bf16x8*)&As[buf][row * 64 + c * 8];
            }
            #pragma unroll
            for (int nt = 0; nt < 4; ++nt) {
                int row = wc * 64 + nt * 16 + li;
                int c = (kk * 4 + g) ^ (row & 7);
                bfr[nt] = *(const bf16x8*)&Bs[buf][row * 64 + c * 8];
            }
            __builtin_amdgcn_s_setprio(1);
            #pragma unroll
            for (int mt = 0; mt < 4; ++mt)
                #pragma unroll
                for (int nt = 0; nt < 4; ++nt)
                    acc[mt][nt] = __builtin_amdgcn_mfma_f32_16x16x32_bf16(
                        af[mt], bfr[nt], acc[mt][nt], 0, 0, 0);
            __builtin_amdgcn_s_setprio(0);
        }
        buf ^= 1;
    }

    // epilogue — C layout: col = lane&15, row = 4*(lane>>4)+j
    const int nloc_base = (bx & 7) * 128;
    #pragma unroll
    for (int mt = 0; mt < 4; ++mt) {
        #pragma unroll
        for (int nt = 0; nt < 4; ++nt) {
            const int nloc = nloc_base + wc * 64 + nt * 16 + li;
            const int h = nloc >> 6, dk = nloc & 63;
            #pragma unroll
            for (int j = 0; j < 4; ++j) {
                const int m = mbase + wr * 64 + mt * 16 + g * 4 + j;
                const int b = m >> 11, s2 = m & (S_LEN - 1);
                float v = acc[mt][nt][j];
                if (seg == 2) {       // V^T
                    Vt[((size_t)((b * NH + h) * DKD + dk)) * S_LEN + s2] = f2b(v);
                } else {              // Q or K with RoPE
                    float pv = __shfl_xor(v, 1);
                    int tt = dk >> 1;
                    float cs = ctab[s2 * 32 + tt];
                    float sn = stab[s2 * 32 + tt];
                    float o = (nloc & 1) ? (pv * sn + v * cs) : (v * cs - pv * sn);
                    size_t off = ((size_t)((b * NH + h) * S_LEN + s2)) * DKD + dk;
                    if (seg == 0) Qb[off] = f2b(o * QSCALE);
                    else          Kb[off] = f2b(o);
                }
            }
        }
    }
}

// ---------------- output GEMM: out[M][1024] = A[M][K] * BT[1024][K]^T, fp32 out ----
// Natural order: gridDim.x=16 => XCD = bx%8 owns 2 B-panels (256 KB L2-resident).
__global__ __launch_bounds__(256) void gemm_out_k(const short* __restrict__ A,
                                                  const short* __restrict__ BT,
                                                  float* __restrict__ Cout) {
    const int K = 1024;
    __shared__ short As[2][128 * 64];   // 32 KB
    __shared__ short Bs[2][64 * 64];    // 16 KB   (total 48 KB -> 3 blocks/CU)

    const int bx = blockIdx.x;          // 0..15
    const int by = blockIdx.y;          // 0..63

    const int t = threadIdx.x;
    const int lane = t & 63;
    const int li = lane & 15;
    const int g  = lane >> 4;
    const int w  = t >> 6;
    const int wr = w >> 1, wc = w & 1;           // 2x2 waves: 64m x 32n each
    const int mbase = by * 128;
    const int nbase = bx * 64;

    f32x4 acc[4][2] = {};

    auto stageAB = [&](int bb, int kt) {
        const int k0 = kt * 64;
        #pragma unroll
        for (int it = 0; it < 4; ++it) {
            int idx = it * 256 + t;
            int r = idx >> 3, p = idx & 7;
            int c = p ^ (r & 7);
            gld_lds16(A + (size_t)(mbase + r) * K + k0 + c * 8, &As[bb][idx * 8]);
        }
        #pragma unroll
        for (int it = 0; it < 2; ++it) {
            int idx = it * 256 + t;
            int r = idx >> 3, p = idx & 7;
            int c = p ^ (r & 7);
            gld_lds16(BT + (size_t)(nbase + r) * K + k0 + c * 8, &Bs[bb][idx * 8]);
        }
    };

    stageAB(0, 0);
    int buf = 0;
    for (int kt = 0; kt < K / 64; ++kt) {
        __syncthreads();
        if (kt + 1 < K / 64) stageAB(buf ^ 1, kt + 1);

        #pragma unroll
        for (int kk = 0; kk < 2; ++kk) {
            bf16x8 af[4], bfr[2];
            #pragma unroll
            for (int mt = 0; mt < 4; ++mt) {
                int row = wr * 64 + mt * 16 + li;
                int c = (kk * 4 + g) ^ (row & 7);
                af[mt] = *(const bf16x8*)&As[buf][row * 64 + c * 8];
            }
            #pragma unroll
            for (int nt = 0; nt < 2; ++nt) {
                int row = wc * 32 + nt * 16 + li;
                int c = (kk * 4 + g) ^ (row & 7);
                bfr[nt] = *(const bf16x8*)&Bs[buf][row * 64 + c * 8];
            }
            __builtin_amdgcn_s_setprio(1);
            #pragma unroll
            for (int mt = 0; mt < 4; ++mt)
                #pragma unroll
                for (int nt = 0; nt < 2; ++nt)
                    acc[mt][nt] = __builtin_amdgcn_mfma_f32_16x16x32_bf16(
                        af[mt], bfr[nt], acc[mt][nt], 0, 0, 0);
            __builtin_amdgcn_s_setprio(0);
        }
        buf ^= 1;
    }

    #pragma unroll
    for (int mt = 0; mt < 4; ++mt)
        #pragma unroll
        for (int nt = 0; nt < 2; ++nt) {
            const int n = nbase + wc * 32 + nt * 16 + li;
            #pragma unroll
            for (int j = 0; j < 4; ++j) {
                const int m = mbase + wr * 64 + mt * 16 + g * 4 + j;
                Cout[(size_t)m * D_DIM + n] = acc[mt][nt][j];
            }
        }
}

// ---------------- flash attention, swapped-QK 32x32 structure (R4-validated) -------
__global__ __launch_bounds__(256, 4) void attn_k(const short* __restrict__ Qb,
                                                 const short* __restrict__ Kb,
                                                 const short* __restrict__ Vt,
                                                 short* __restrict__ Ao) {
    __shared__ short Ks[2][64 * 64];
    __shared__ short Vs[2][64 * 64];

    const int braw = blockIdx.y * 16 + blockIdx.x;   // nwg=1024
    const int tile = (braw & 7) * 128 + (braw >> 3);
    const int bxs = tile & 15, bh = tile >> 4;       // blocks sharing bh -> same XCD

    const int t = threadIdx.x;
    const int lane = t & 63;
    const int ql = lane & 31;
    const int hi = lane >> 5;
    const int w  = t >> 6;
    const int q0 = bxs * 128;

    // Q fragments (B-operand): lane holds Q[q=ql][k = kb*16 + hi*8 + i]
    bf16x8 aq[4];
    {
        const short* qp = Qb + ((size_t)bh * S_LEN + q0 + w * 32 + ql) * DKD;
        #pragma unroll
        for (int kb = 0; kb < 4; ++kb)
            aq[kb] = *(const bf16x8*)(qp + kb * 16 + hi * 8);
    }

    f32x16 oacc[2] = {};
    float mrun = -INFINITY, lsum = 0.f;

    auto stageKV = [&](int bb, int kt) {
        const int kb = kt * 64;
        #pragma unroll
        for (int it = 0; it < 2; ++it) {
            int idx = it * 256 + t;
            int r = idx >> 3, p = idx & 7;
            int c = p ^ (r & 7);
            gld_lds16(Kb + ((size_t)bh * S_LEN + kb + r) * DKD + c * 8, &Ks[bb][idx * 8]);
        }
        #pragma unroll
        for (int it = 0; it < 2; ++it) {
            int idx = it * 256 + t;
            int r = idx >> 3, p = idx & 7;
            int c = p ^ (r & 7);
            gld_lds16(Vt + ((size_t)bh * DKD + r) * S_LEN + kb + c * 8, &Vs[bb][idx * 8]);
        }
    };

    stageKV(0, 0);
    int buf = 0;
    for (int kt = 0; kt < S_LEN / 64; ++kt) {
        __syncthreads();                                   // staged tile ready
        if (kt + 1 < S_LEN / 64) stageKV(buf ^ 1, kt + 1); // prefetch next

        const short* KsB = Ks[buf];
        const short* VsB = Vs[buf];

        // S^T = K·Q^T   (already in exp2 domain via QSCALE)
        f32x16 s0 = {}, s1 = {};
        __builtin_amdgcn_s_setprio(1);
        #pragma unroll
        for (int kb = 0; kb < 4; ++kb) {
            const int ch = ((kb * 2 + hi) ^ (ql & 7)) * 8;
            bf16x8 k0 = *(const bf16x8*)&KsB[ql * 64 + ch];
            bf16x8 k1 = *(const bf16x8*)&KsB[(ql + 32) * 64 + ch];
            s0 = __builtin_amdgcn_mfma_f32_32x32x16_bf16(k0, aq[kb], s0, 0, 0, 0);
            s1 = __builtin_amdgcn_mfma_f32_32x32x16_bf16(k1, aq[kb], s1, 0, 0, 0);
        }
        __builtin_amdgcn_s_setprio(0);

        // tile row-max: per-lane tree + one cross-half shfl (R2-proven)
        float pmax;
        {
            float m0 = fmaxf(fmaxf(s0[0], s0[1]), fmaxf(s0[2], s0[3]));
            float m1 = fmaxf(fmaxf(s0[4], s0[5]), fmaxf(s0[6], s0[7]));
            float m2 = fmaxf(fmaxf(s0[8], s0[9]), fmaxf(s0[10], s0[11]));
            float m3 = fmaxf(fmaxf(s0[12], s0[13]), fmaxf(s0[14], s0[15]));
            float m4 = fmaxf(fmaxf(s1[0], s1[1]), fmaxf(s1[2], s1[3]));
            float m5 = fmaxf(fmaxf(s1[4], s1[5]), fmaxf(s1[6], s1[7]));
            float m6 = fmaxf(fmaxf(s1[8], s1[9]), fmaxf(s1[10], s1[11]));
            float m7 = fmaxf(fmaxf(s1[12], s1[13]), fmaxf(s1[14], s1[15]));
            pmax = fmaxf(fmaxf(fmaxf(m0, m1), fmaxf(m2, m3)),
                         fmaxf(fmaxf(m4, m5), fmaxf(m6, m7)));
            pmax = fmaxf(pmax, __shfl_xor(pmax, 32));
        }

        // defer-max: rescale only on significant growth (11.5 = 8 nats in 2-domain)
        if (__any(pmax > mrun + 11.5f)) {
            float scl = fast_exp2(mrun - pmax);
            lsum *= scl;
            #pragma unroll
            for (int r = 0; r < 16; ++r) { oacc[0][r] *= scl; oacc[1][r] *= scl; }
            mrun = pmax;
        }

        // P = exp2(S - m), in place; accumulate row sum
        float rs0 = 0.f, rs1 = 0.f;
        #pragma unroll
        for (int r = 0; r < 16; ++r) {
            s0[r] = fast_exp2(s0[r] - mrun); rs0 += s0[r];
            s1[r] = fast_exp2(s1[r] - mrun); rs1 += s1[r];
        }
        float rs = rs0 + rs1;
        rs += __shfl_xor(rs, 32);
        lsum += rs;

        // pack P into PV B-fragments: cvt_pk pairs + permlane32_swap (T12)
        bf16x8 pb[4];
        #pragma unroll
        for (int kb2 = 0; kb2 < 2; ++kb2) {
            uint32_t A0 = cvtpk(s0[kb2 * 8 + 0], s0[kb2 * 8 + 1]);
            uint32_t A1 = cvtpk(s0[kb2 * 8 + 2], s0[kb2 * 8 + 3]);
            uint32_t A2 = cvtpk(s0[kb2 * 8 + 4], s0[kb2 * 8 + 5]);
            uint32_t A3 = cvtpk(s0[kb2 * 8 + 6], s0[kb2 * 8 + 7]);
            pl32swap(A0, A2); pl32swap(A1, A3);
            union { uint32_t u[4]; bf16x8 v; } pk;
            pk.u[0] = A0; pk.u[1] = A1; pk.u[2] = A2; pk.u[3] = A3;
            pb[kb2] = pk.v;

            uint32_t B0 = cvtpk(s1[kb2 * 8 + 0], s1[kb2 * 8 + 1]);
            uint32_t B1 = cvtpk(s1[kb2 * 8 + 2], s1[kb2 * 8 + 3]);
            uint32_t B2 = cvtpk(s1[kb2 * 8 + 4], s1[kb2 * 8 + 5]);
            uint32_t B3 = cvtpk(s1[kb2 * 8 + 6], s1[kb2 * 8 + 7]);
            pl32swap(B0, B2); pl32swap(B1, B3);
            union { uint32_t u[4]; bf16x8 v; } pk2;
            pk2.u[0] = B0; pk2.u[1] = B1; pk2.u[2] = B2; pk2.u[3] = B3;
            pb[2 + kb2] = pk2.v;
        }

        // O^T += V^T · P^T
        __builtin_amdgcn_s_setprio(1);
        #pragma unroll
        for (int ds = 0; ds < 2; ++ds)
            #pragma unroll
            for (int kb = 0; kb < 4; ++kb) {
                const int ch = ((kb * 2 + hi) ^ (ql & 7)) * 8;
                bf16x8 vf = *(const bf16x8*)&VsB[(ds * 32 + ql) * 64 + ch];
                oacc[ds] = __builtin_amdgcn_mfma_f32_32x32x16_bf16(vf, pb[kb], oacc[ds], 0, 0, 0);
            }
        __builtin_amdgcn_s_setprio(0);
        buf ^= 1;
    }

    // epilogue: lane owns q = q0 + w*32 + ql entirely
    const float inv = 1.0f / lsum;
    const int b = bh >> 4, h = bh & 15;
    short* op = Ao + ((size_t)(b * S_LEN + q0 + w * 32 + ql)) * D_DIM + h * DKD;
    #pragma unroll
    for (int ds = 0; ds < 2; ++ds)
        #pragma unroll
        for (int r4 = 0; r4 < 4; ++r4) {
            uint2 pk;
            pk.x = cvtpk(oacc[ds][r4 * 4 + 0] * inv, oacc[ds][r4 * 4 + 1] * inv);
            pk.y = cvtpk(oacc[ds][r4 * 4 + 2] * inv, oacc[ds][r4 * 4 + 3] * inv);
            *(uint2*)(op + ds * 32 + r4 * 8 + hi * 4) = pk;
        }
}

// ---------------- launch ----------------
extern "C" void kernel_launch(void* const* d_in, const int* in_sizes, int n_in,
                              void* d_out, int out_size, void* d_ws, size_t ws_size,
                              hipStream_t stream) {
    const float* x  = (const float*)d_in[0];
    const float* Wq = (const float*)d_in[2];
    const float* Wk = (const float*)d_in[3];
    const float* Wv = (const float*)d_in[4];
    const float* Wo = (const float*)d_in[5];

    char* ws = (char*)d_ws;
    short* xb  = (short*)(ws);                         // 16 MB
    short* Wqt = (short*)(ws + (size_t)(16 << 20));    // 2 MB each, Wq/Wk/Wv contiguous
    short* Wkt = (short*)(ws + (size_t)(18 << 20));
    short* Wvt = (short*)(ws + (size_t)(20 << 20));
    short* Wot = (short*)(ws + (size_t)(22 << 20));
    short* Qb  = (short*)(ws + (size_t)(24 << 20));    // 16 MB [BH][S][DK]
    short* Kb  = (short*)(ws + (size_t)(40 << 20));    // 16 MB
    short* Vt  = (short*)(ws + (size_t)(56 << 20));    // 16 MB [BH][DK][S]
    short* Ao  = (short*)(ws + (size_t)(72 << 20));    // 16 MB [B][S][D]
    float* ctab = (float*)(ws + (size_t)(88 << 20));   // 256 KB
    float* stab = (float*)(ws + (size_t)(88 << 20) + (1 << 18));

    cast_x_k<<<4096, 256, 0, stream>>>(x, xb);
    cast_wt_k<<<dim3(32, 32, 4), dim3(32, 8), 0, stream>>>(Wq, Wk, Wv, Wo, Wqt, Wkt, Wvt, Wot);
    rope_tab_k<<<256, 256, 0, stream>>>(ctab, stab);

    gemm_qkv_k<<<dim3(24, 64), 256, 0, stream>>>(xb, Wqt, Qb, Kb, Vt, ctab, stab);

    attn_k<<<dim3(16, 64), 256, 0, stream>>>(Qb, Kb, Vt, Ao);

    gemm_out_k<<<dim3(16, 64), 256, 0, stream>>>(Ao, Wot, (float*)d_out);
}

// Round 7
// 228.486 us; speedup vs baseline: 1.1073x; 1.1073x over previous
//
#include <hip/hip_runtime.h>
#include <cstdint>
#include <cmath>

#define S_LEN 2048
#define D_DIM 1024
#define NH    16
#define DKD   64
#define BATCH 4
#define M_TOT (BATCH * S_LEN)   // 8192

// 0.125 * log2(e): folded into Q so QK^T lands directly in exp2 domain
#define QSCALE 0.18033688011112042f

typedef __attribute__((ext_vector_type(8)))  short bf16x8;
typedef __attribute__((ext_vector_type(4)))  float f32x4;
typedef __attribute__((ext_vector_type(16))) float f32x16;

typedef __attribute__((address_space(1))) void as1_void;
typedef __attribute__((address_space(3))) void as3_void;

__device__ __forceinline__ short f2b(float f) {
    union { float f; uint32_t u; } v; v.f = f;
    uint32_t r = v.u + 0x7fffu + ((v.u >> 16) & 1u);   // RNE
    return (short)(r >> 16);
}

__device__ __forceinline__ void gld_lds16(const void* g, void* l) {
    __builtin_amdgcn_global_load_lds((as1_void*)g, (as3_void*)l, 16, 0, 0);
}

__device__ __forceinline__ float fast_exp2(float x) {
#if __has_builtin(__builtin_amdgcn_exp2f)
    return __builtin_amdgcn_exp2f(x);
#else
    return exp2f(x);
#endif
}

__device__ __forceinline__ uint32_t cvtpk(float lo, float hi) {
    uint32_t r;
    asm("v_cvt_pk_bf16_f32 %0, %1, %2" : "=v"(r) : "v"(lo), "v"(hi));
    return r;
}

// two genuinely-distinct values: validated by R2 (T12 packing)
__device__ __forceinline__ void pl32swap(uint32_t& a, uint32_t& b) {
    asm volatile("v_permlane32_swap_b32 %0, %1" : "+v"(a), "+v"(b));
}

// ---------------- cast x (fp32 -> bf16), 8 elems/thread ----------------
__global__ __launch_bounds__(256) void cast_x_k(const float* __restrict__ x,
                                                short* __restrict__ xb) {
    size_t i = (size_t)blockIdx.x * 256 + threadIdx.x;
    const float4* p = (const float4*)x + i * 2;
    float4 a = p[0], b = p[1];
    bf16x8 o;
    o[0]=f2b(a.x); o[1]=f2b(a.y); o[2]=f2b(a.z); o[3]=f2b(a.w);
    o[4]=f2b(b.x); o[5]=f2b(b.y); o[6]=f2b(b.z); o[7]=f2b(b.w);
    *((bf16x8*)xb + i) = o;
}

// ---------------- transpose + cast weights: Wt[n][k] = W[k][n] ----------------
__global__ __launch_bounds__(256) void cast_wt_k(const float* w0, const float* w1,
                                                 const float* w2, const float* w3,
                                                 short* o0, short* o1, short* o2, short* o3) {
    __shared__ float tile[32][33];
    const float* src = blockIdx.z == 0 ? w0 : blockIdx.z == 1 ? w1 : blockIdx.z == 2 ? w2 : w3;
    short*       dst = blockIdx.z == 0 ? o0 : blockIdx.z == 1 ? o1 : blockIdx.z == 2 ? o2 : o3;
    int tx = threadIdx.x, ty = threadIdx.y;
    int bx = blockIdx.x * 32, by = blockIdx.y * 32;
    #pragma unroll
    for (int i = 0; i < 4; ++i)
        tile[ty * 4 + i][tx] = src[(size_t)(by + ty * 4 + i) * D_DIM + bx + tx];
    __syncthreads();
    #pragma unroll
    for (int i = 0; i < 4; ++i)
        dst[(size_t)(bx + ty * 4 + i) * D_DIM + by + tx] = f2b(tile[tx][ty * 4 + i]);
}

// ---------------- RoPE table: ctab/stab [S][32] ----------------
__global__ __launch_bounds__(256) void rope_tab_k(float* __restrict__ ct, float* __restrict__ st) {
    int i = blockIdx.x * 256 + threadIdx.x;      // 2048*32 = 65536
    int s = i >> 5, tt = i & 31;
    float inv = (float)pow(10000.0, -(double)(2 * tt) / 64.0);
    float ang = (float)s * inv;
    float sn, cs;
    sincosf(ang, &sn, &cs);
    ct[i] = cs; st[i] = sn;
}

// ---------------- GEMM: C[M][N] = A[M][K] * BT[N][K]^T  (R2-proven structure) ------
// MODE 0: -> Q  [BH][S][DK] bf16, RoPE applied, pre-scaled by QSCALE
// MODE 1: -> K  [BH][S][DK] bf16, RoPE applied
// MODE 3: -> out [M][N] fp32
template <int MODE>
__global__ __launch_bounds__(256) void gemm_bt_k(const short* __restrict__ A,
                                                 const short* __restrict__ BT,
                                                 void* __restrict__ Cout,
                                                 const float* __restrict__ ctab,
                                                 const float* __restrict__ stab) {
    const int K = 1024;
    __shared__ short As[128 * 64];   // 16 KB, chunk-swizzled
    __shared__ short Bs[128 * 64];

    const int t = threadIdx.x;
    const int lane = t & 63;
    const int li = lane & 15;
    const int g  = lane >> 4;
    const int w  = t >> 6;
    const int wr = w >> 1, wc = w & 1;
    const int mbase = blockIdx.y * 128;
    const int nbase = blockIdx.x * 128;

    f32x4 acc[4][4] = {};

    for (int kt = 0; kt < K / 64; ++kt) {
        const int k0 = kt * 64;
        #pragma unroll
        for (int it = 0; it < 4; ++it) {
            int idx = it * 256 + t;
            int r = idx >> 3, p = idx & 7;
            int c = p ^ (r & 7);
            gld_lds16(A + (size_t)(mbase + r) * K + k0 + c * 8, &As[idx * 8]);
        }
        #pragma unroll
        for (int it = 0; it < 4; ++it) {
            int idx = it * 256 + t;
            int r = idx >> 3, p = idx & 7;
            int c = p ^ (r & 7);
            gld_lds16(BT + (size_t)(nbase + r) * K + k0 + c * 8, &Bs[idx * 8]);
        }
        __syncthreads();

        #pragma unroll
        for (int kk = 0; kk < 2; ++kk) {
            bf16x8 af[4], bfr[4];
            #pragma unroll
            for (int mt = 0; mt < 4; ++mt) {
                int row = wr * 64 + mt * 16 + li;
                int c = (kk * 4 + g) ^ (row & 7);
                af[mt] = *(const bf16x8*)&As[row * 64 + c * 8];
            }
            #pragma unroll
            for (int nt = 0; nt < 4; ++nt) {
                int row = wc * 64 + nt * 16 + li;
                int c = (kk * 4 + g) ^ (row & 7);
                bfr[nt] = *(const bf16x8*)&Bs[row * 64 + c * 8];
            }
            #pragma unroll
            for (int mt = 0; mt < 4; ++mt)
                #pragma unroll
                for (int nt = 0; nt < 4; ++nt)
                    acc[mt][nt] = __builtin_amdgcn_mfma_f32_16x16x32_bf16(
                        af[mt], bfr[nt], acc[mt][nt], 0, 0, 0);
        }
        __syncthreads();
    }

    // epilogue — C layout: col = lane&15, row = 4*(lane>>4)+j
    #pragma unroll
    for (int mt = 0; mt < 4; ++mt) {
        #pragma unroll
        for (int nt = 0; nt < 4; ++nt) {
            const int n = nbase + wc * 64 + nt * 16 + li;
            #pragma unroll
            for (int j = 0; j < 4; ++j) {
                const int m = mbase + wr * 64 + mt * 16 + g * 4 + j;
                float v = acc[mt][nt][j];
                if (MODE == 3) {
                    ((float*)Cout)[(size_t)m * D_DIM + n] = v;
                } else {  // Q or K with RoPE
                    float pv = __shfl_xor(v, 1);
                    int s2 = m & (S_LEN - 1);
                    int tt = (n & 63) >> 1;
                    float cs = ctab[s2 * 32 + tt];
                    float sn = stab[s2 * 32 + tt];
                    float o = (n & 1) ? (pv * sn + v * cs) : (v * cs - pv * sn);
                    if (MODE == 0) o *= QSCALE;
                    int b = m >> 11, h = n >> 6, dk = n & 63;
                    ((short*)Cout)[((size_t)((b * NH + h) * S_LEN + s2)) * DKD + dk] = f2b(o);
                }
            }
        }
    }
}

// ---------------- V GEMM: same main loop, LDS-transpose epilogue -> coalesced V^T ---
// Output V^T[BH][DK][S]: C-tile staged to LDS [nloc 128][mloc 128] (XOR-chunked),
// then each 16-lane group stores one contiguous 256B row segment.
__global__ __launch_bounds__(256) void gemm_v_k(const short* __restrict__ A,
                                                const short* __restrict__ BT,
                                                short* __restrict__ Vt) {
    const int K = 1024;
    __shared__ __align__(16) short smem[2 * 128 * 64];   // As|Bs, reused for C-stage
    short* As = smem;
    short* Bs = smem + 128 * 64;

    const int t = threadIdx.x;
    const int lane = t & 63;
    const int li = lane & 15;
    const int g  = lane >> 4;
    const int w  = t >> 6;
    const int wr = w >> 1, wc = w & 1;
    const int mbase = blockIdx.y * 128;
    const int nbase = blockIdx.x * 128;

    f32x4 acc[4][4] = {};

    for (int kt = 0; kt < K / 64; ++kt) {
        const int k0 = kt * 64;
        #pragma unroll
        for (int it = 0; it < 4; ++it) {
            int idx = it * 256 + t;
            int r = idx >> 3, p = idx & 7;
            int c = p ^ (r & 7);
            gld_lds16(A + (size_t)(mbase + r) * K + k0 + c * 8, &As[idx * 8]);
        }
        #pragma unroll
        for (int it = 0; it < 4; ++it) {
            int idx = it * 256 + t;
            int r = idx >> 3, p = idx & 7;
            int c = p ^ (r & 7);
            gld_lds16(BT + (size_t)(nbase + r) * K + k0 + c * 8, &Bs[idx * 8]);
        }
        __syncthreads();

        #pragma unroll
        for (int kk = 0; kk < 2; ++kk) {
            bf16x8 af[4], bfr[4];
            #pragma unroll
            for (int mt = 0; mt < 4; ++mt) {
                int row = wr * 64 + mt * 16 + li;
                int c = (kk * 4 + g) ^ (row & 7);
                af[mt] = *(const bf16x8*)&As[row * 64 + c * 8];
            }
            #pragma unroll
            for (int nt = 0; nt < 4; ++nt) {
                int row = wc * 64 + nt * 16 + li;
                int c = (kk * 4 + g) ^ (row & 7);
                bfr[nt] = *(const bf16x8*)&Bs[row * 64 + c * 8];
            }
            #pragma unroll
            for (int mt = 0; mt < 4; ++mt)
                #pragma unroll
                for (int nt = 0; nt < 4; ++nt)
                    acc[mt][nt] = __builtin_amdgcn_mfma_f32_16x16x32_bf16(
                        af[mt], bfr[nt], acc[mt][nt], 0, 0, 0);
        }
        __syncthreads();   // also protects smem reuse below
    }

    // stage C^T tile: smem[nloc][mloc], chunk-XOR layout (16 chunks of 8 shorts/row)
    #pragma unroll
    for (int mt = 0; mt < 4; ++mt) {
        #pragma unroll
        for (int nt = 0; nt < 4; ++nt) {
            const int nloc = wc * 64 + nt * 16 + li;
            #pragma unroll
            for (int j = 0; j < 4; ++j) {
                const int mloc = wr * 64 + mt * 16 + g * 4 + j;
                smem[nloc * 128 + (((mloc >> 3) ^ (nloc & 7)) << 3) + (mloc & 7)] =
                    f2b(acc[mt][nt][j]);
            }
        }
    }
    __syncthreads();

    // read back rows; 16 lanes cover one contiguous 256B V^T row segment
    const int b = mbase >> 11, s2 = mbase & (S_LEN - 1);
    #pragma unroll
    for (int rr = 0; rr < 8; ++rr) {
        const int row = w * 32 + rr * 4 + (lane >> 4);   // nloc
        const int mc  = lane & 15;
        const int phys = mc ^ (row & 7);
        bf16x8 vrow = *(const bf16x8*)&smem[row * 128 + phys * 8];
        const int n = nbase + row;
        const int h = n >> 6, dk = n & 63;
        *(bf16x8*)&Vt[((size_t)((b * NH + h) * DKD + dk)) * S_LEN + s2 + mc * 8] = vrow;
    }
}

// ---------------- flash attention, swapped-QK 32x32 structure (R4/R5-validated) ----
__global__ __launch_bounds__(256, 4) void attn_k(const short* __restrict__ Qb,
                                                 const short* __restrict__ Kb,
                                                 const short* __restrict__ Vt,
                                                 short* __restrict__ Ao) {
    __shared__ short Ks[2][64 * 64];
    __shared__ short Vs[2][64 * 64];

    const int braw = blockIdx.y * 16 + blockIdx.x;   // nwg=1024
    const int tile = (braw & 7) * 128 + (braw >> 3);
    const int bxs = tile & 15, bh = tile >> 4;       // blocks sharing bh -> same XCD

    const int t = threadIdx.x;
    const int lane = t & 63;
    const int ql = lane & 31;
    const int hi = lane >> 5;
    const int w  = t >> 6;
    const int q0 = bxs * 128;

    // Q fragments (B-operand): lane holds Q[q=ql][k = kb*16 + hi*8 + i]
    bf16x8 aq[4];
    {
        const short* qp = Qb + ((size_t)bh * S_LEN + q0 + w * 32 + ql) * DKD;
        #pragma unroll
        for (int kb = 0; kb < 4; ++kb)
            aq[kb] = *(const bf16x8*)(qp + kb * 16 + hi * 8);
    }

    f32x16 oacc[2] = {};
    float mrun = -INFINITY, lsum = 0.f;

    auto stageKV = [&](int bb, int kt) {
        const int kb = kt * 64;
        #pragma unroll
        for (int it = 0; it < 2; ++it) {
            int idx = it * 256 + t;
            int r = idx >> 3, p = idx & 7;
            int c = p ^ (r & 7);
            gld_lds16(Kb + ((size_t)bh * S_LEN + kb + r) * DKD + c * 8, &Ks[bb][idx * 8]);
        }
        #pragma unroll
        for (int it = 0; it < 2; ++it) {
            int idx = it * 256 + t;
            int r = idx >> 3, p = idx & 7;
            int c = p ^ (r & 7);
            gld_lds16(Vt + ((size_t)bh * DKD + r) * S_LEN + kb + c * 8, &Vs[bb][idx * 8]);
        }
    };

    stageKV(0, 0);
    int buf = 0;
    for (int kt = 0; kt < S_LEN / 64; ++kt) {
        __syncthreads();                                   // staged tile ready
        if (kt + 1 < S_LEN / 64) stageKV(buf ^ 1, kt + 1); // prefetch next

        const short* KsB = Ks[buf];
        const short* VsB = Vs[buf];

        // S^T = K·Q^T   (already in exp2 domain via QSCALE)
        f32x16 s0 = {}, s1 = {};
        __builtin_amdgcn_s_setprio(1);
        #pragma unroll
        for (int kb = 0; kb < 4; ++kb) {
            const int ch = ((kb * 2 + hi) ^ (ql & 7)) * 8;
            bf16x8 k0 = *(const bf16x8*)&KsB[ql * 64 + ch];
            bf16x8 k1 = *(const bf16x8*)&KsB[(ql + 32) * 64 + ch];
            s0 = __builtin_amdgcn_mfma_f32_32x32x16_bf16(k0, aq[kb], s0, 0, 0, 0);
            s1 = __builtin_amdgcn_mfma_f32_32x32x16_bf16(k1, aq[kb], s1, 0, 0, 0);
        }
        __builtin_amdgcn_s_setprio(0);

        // tile row-max: per-lane tree + one cross-half shfl (R2-proven)
        float pmax;
        {
            float m0 = fmaxf(fmaxf(s0[0], s0[1]), fmaxf(s0[2], s0[3]));
            float m1 = fmaxf(fmaxf(s0[4], s0[5]), fmaxf(s0[6], s0[7]));
            float m2 = fmaxf(fmaxf(s0[8], s0[9]), fmaxf(s0[10], s0[11]));
            float m3 = fmaxf(fmaxf(s0[12], s0[13]), fmaxf(s0[14], s0[15]));
            float m4 = fmaxf(fmaxf(s1[0], s1[1]), fmaxf(s1[2], s1[3]));
            float m5 = fmaxf(fmaxf(s1[4], s1[5]), fmaxf(s1[6], s1[7]));
            float m6 = fmaxf(fmaxf(s1[8], s1[9]), fmaxf(s1[10], s1[11]));
            float m7 = fmaxf(fmaxf(s1[12], s1[13]), fmaxf(s1[14], s1[15]));
            pmax = fmaxf(fmaxf(fmaxf(m0, m1), fmaxf(m2, m3)),
                         fmaxf(fmaxf(m4, m5), fmaxf(m6, m7)));
            pmax = fmaxf(pmax, __shfl_xor(pmax, 32));
        }

        // defer-max: rescale only on significant growth (11.5 = 8 nats in 2-domain)
        if (__any(pmax > mrun + 11.5f)) {
            float scl = fast_exp2(mrun - pmax);
            lsum *= scl;
            #pragma unroll
            for (int r = 0; r < 16; ++r) { oacc[0][r] *= scl; oacc[1][r] *= scl; }
            mrun = pmax;
        }

        // P = exp2(S - m), in place; accumulate row sum
        float rs0 = 0.f, rs1 = 0.f;
        #pragma unroll
        for (int r = 0; r < 16; ++r) {
            s0[r] = fast_exp2(s0[r] - mrun); rs0 += s0[r];
            s1[r] = fast_exp2(s1[r] - mrun); rs1 += s1[r];
        }
        float rs = rs0 + rs1;
        rs += __shfl_xor(rs, 32);
        lsum += rs;

        // pack P into PV B-fragments: cvt_pk pairs + permlane32_swap (T12)
        bf16x8 pb[4];
        #pragma unroll
        for (int kb2 = 0; kb2 < 2; ++kb2) {
            uint32_t A0 = cvtpk(s0[kb2 * 8 + 0], s0[kb2 * 8 + 1]);
            uint32_t A1 = cvtpk(s0[kb2 * 8 + 2], s0[kb2 * 8 + 3]);
            uint32_t A2 = cvtpk(s0[kb2 * 8 + 4], s0[kb2 * 8 + 5]);
            uint32_t A3 = cvtpk(s0[kb2 * 8 + 6], s0[kb2 * 8 + 7]);
            pl32swap(A0, A2); pl32swap(A1, A3);
            union { uint32_t u[4]; bf16x8 v; } pk;
            pk.u[0] = A0; pk.u[1] = A1; pk.u[2] = A2; pk.u[3] = A3;
            pb[kb2] = pk.v;

            uint32_t B0 = cvtpk(s1[kb2 * 8 + 0], s1[kb2 * 8 + 1]);
            uint32_t B1 = cvtpk(s1[kb2 * 8 + 2], s1[kb2 * 8 + 3]);
            uint32_t B2 = cvtpk(s1[kb2 * 8 + 4], s1[kb2 * 8 + 5]);
            uint32_t B3 = cvtpk(s1[kb2 * 8 + 6], s1[kb2 * 8 + 7]);
            pl32swap(B0, B2); pl32swap(B1, B3);
            union { uint32_t u[4]; bf16x8 v; } pk2;
            pk2.u[0] = B0; pk2.u[1] = B1; pk2.u[2] = B2; pk2.u[3] = B3;
            pb[2 + kb2] = pk2.v;
        }

        // O^T += V^T · P^T
        __builtin_amdgcn_s_setprio(1);
        #pragma unroll
        for (int ds = 0; ds < 2; ++ds)
            #pragma unroll
            for (int kb = 0; kb < 4; ++kb) {
                const int ch = ((kb * 2 + hi) ^ (ql & 7)) * 8;
                bf16x8 vf = *(const bf16x8*)&VsB[(ds * 32 + ql) * 64 + ch];
                oacc[ds] = __builtin_amdgcn_mfma_f32_32x32x16_bf16(vf, pb[kb], oacc[ds], 0, 0, 0);
            }
        __builtin_amdgcn_s_setprio(0);
        buf ^= 1;
    }

    // epilogue: lane owns q = q0 + w*32 + ql entirely
    const float inv = 1.0f / lsum;
    const int b = bh >> 4, h = bh & 15;
    short* op = Ao + ((size_t)(b * S_LEN + q0 + w * 32 + ql)) * D_DIM + h * DKD;
    #pragma unroll
    for (int ds = 0; ds < 2; ++ds)
        #pragma unroll
        for (int r4 = 0; r4 < 4; ++r4) {
            uint2 pk;
            pk.x = cvtpk(oacc[ds][r4 * 4 + 0] * inv, oacc[ds][r4 * 4 + 1] * inv);
            pk.y = cvtpk(oacc[ds][r4 * 4 + 2] * inv, oacc[ds][r4 * 4 + 3] * inv);
            *(uint2*)(op + ds * 32 + r4 * 8 + hi * 4) = pk;
        }
}

// ---------------- launch ----------------
extern "C" void kernel_launch(void* const* d_in, const int* in_sizes, int n_in,
                              void* d_out, int out_size, void* d_ws, size_t ws_size,
                              hipStream_t stream) {
    const float* x  = (const float*)d_in[0];
    const float* Wq = (const float*)d_in[2];
    const float* Wk = (const float*)d_in[3];
    const float* Wv = (const float*)d_in[4];
    const float* Wo = (const float*)d_in[5];

    char* ws = (char*)d_ws;
    short* xb  = (short*)(ws);                         // 16 MB
    short* Wqt = (short*)(ws + (size_t)(16 << 20));    // 2 MB each
    short* Wkt = (short*)(ws + (size_t)(18 << 20));
    short* Wvt = (short*)(ws + (size_t)(20 << 20));
    short* Wot = (short*)(ws + (size_t)(22 << 20));
    short* Qb  = (short*)(ws + (size_t)(24 << 20));    // 16 MB [BH][S][DK]
    short* Kb  = (short*)(ws + (size_t)(40 << 20));    // 16 MB
    short* Vt  = (short*)(ws + (size_t)(56 << 20));    // 16 MB [BH][DK][S]
    short* Ao  = (short*)(ws + (size_t)(72 << 20));    // 16 MB [B][S][D]
    float* ctab = (float*)(ws + (size_t)(88 << 20));   // 256 KB
    float* stab = (float*)(ws + (size_t)(88 << 20) + (1 << 18));

    cast_x_k<<<4096, 256, 0, stream>>>(x, xb);
    cast_wt_k<<<dim3(32, 32, 4), dim3(32, 8), 0, stream>>>(Wq, Wk, Wv, Wo, Wqt, Wkt, Wvt, Wot);
    rope_tab_k<<<256, 256, 0, stream>>>(ctab, stab);

    gemm_bt_k<0><<<dim3(8, 64), 256, 0, stream>>>(xb, Wqt, Qb, ctab, stab);
    gemm_bt_k<1><<<dim3(8, 64), 256, 0, stream>>>(xb, Wkt, Kb, ctab, stab);
    gemm_v_k<<<dim3(8, 64), 256, 0, stream>>>(xb, Wvt, Vt);

    attn_k<<<dim3(16, 64), 256, 0, stream>>>(Qb, Kb, Vt, Ao);

    gemm_bt_k<3><<<dim3(8, 64), 256, 0, stream>>>(Ao, Wot, (float*)d_out, nullptr, nullptr);
}